// Round 1
// 562.509 us; speedup vs baseline: 1.0500x; 1.0500x over previous
//
#include <hip/hip_runtime.h>
#include <math.h>

#define D_DIM 1024
#define MAX_TILES 40   // worst-case sum of ceil(cnt_e/128) = 32 + 7 < 40

typedef __attribute__((ext_vector_type(4))) float f32x4;
typedef __attribute__((ext_vector_type(8))) short s16x8;

__device__ __forceinline__ unsigned short f2bf(float f){
  union { float f; unsigned u; } v; v.f = f;
  unsigned r = v.u + 0x7FFFu + ((v.u >> 16) & 1u);   // RNE; inputs finite
  return (unsigned short)(r >> 16);
}

__device__ __forceinline__ void gld_lds16(const unsigned short* g, unsigned short* l){
  __builtin_amdgcn_global_load_lds(
      (const __attribute__((address_space(1))) unsigned int*)g,
      (__attribute__((address_space(3))) unsigned int*)l, 16, 0, 0);
}

// ---------------- router: fp64 logits, argmax, w_t, aux-loss sums ----------------
__global__ __launch_bounds__(256) void router_kernel(
    const float* __restrict__ x, const float* __restrict__ gumbel,
    const float* __restrict__ rw, const float* __restrict__ rb,
    int* __restrict__ expert_id, float* __restrict__ wtok,
    double* __restrict__ prob_sums, int* __restrict__ counts)
{
  int wave = threadIdx.x >> 6, lane = threadIdx.x & 63;
  int t = blockIdx.x * 4 + wave;
  const float* xr = x + (size_t)t * D_DIM;
  double acc[8];
  #pragma unroll
  for (int e = 0; e < 8; e++) acc[e] = 0.0;
  #pragma unroll
  for (int i = 0; i < 16; i++){
    int d = i * 64 + lane;
    double xv = (double)xr[d];
    const float4* rwp = (const float4*)(rw + (size_t)d * 8);
    float4 r0 = rwp[0], r1 = rwp[1];
    acc[0] += xv * (double)r0.x; acc[1] += xv * (double)r0.y;
    acc[2] += xv * (double)r0.z; acc[3] += xv * (double)r0.w;
    acc[4] += xv * (double)r1.x; acc[5] += xv * (double)r1.y;
    acc[6] += xv * (double)r1.z; acc[7] += xv * (double)r1.w;
  }
  #pragma unroll
  for (int e = 0; e < 8; e++){
    #pragma unroll
    for (int off = 32; off; off >>= 1) acc[e] += __shfl_xor(acc[e], off);
  }
  double logit[8], z[8];
  #pragma unroll
  for (int e = 0; e < 8; e++){
    logit[e] = acc[e] + (double)rb[e];
    z[e] = logit[e] + (double)gumbel[(size_t)t * 8 + e];
  }
  int amax = 0;
  #pragma unroll
  for (int e = 1; e < 8; e++) if (z[e] > z[amax]) amax = e;   // first-max like jnp.argmax
  float zm = (float)z[amax];
  float se = 0.f;
  #pragma unroll
  for (int e = 0; e < 8; e++) se += expf((float)z[e] - zm);
  float y = 1.f / se;                 // y_soft at argmax
  float w = (1.0f - y) + y;           // replicate ref fp32 arithmetic
  double lm = logit[0];
  #pragma unroll
  for (int e = 1; e < 8; e++) lm = fmax(lm, logit[e]);
  float p[8]; float ps = 0.f;
  #pragma unroll
  for (int e = 0; e < 8; e++){ p[e] = expf((float)(logit[e] - lm)); ps += p[e]; }
  float inv = 1.f / ps;

  __shared__ float sprob[4][8];
  if (lane == 0){
    expert_id[t] = amax; wtok[t] = w;
    atomicAdd(&counts[amax], 1);
    #pragma unroll
    for (int e = 0; e < 8; e++) sprob[wave][e] = p[e] * inv;
  }
  __syncthreads();
  if (threadIdx.x < 8){
    double s = (double)sprob[0][threadIdx.x] + (double)sprob[1][threadIdx.x]
             + (double)sprob[2][threadIdx.x] + (double)sprob[3][threadIdx.x];
    atomicAdd(&prob_sums[threadIdx.x], s);
  }
}

// ---------------- finalize: offsets/cursors + flattened 128-row tile list + aux loss ----------------
__global__ void finalize_kernel(const double* __restrict__ prob_sums, const int* __restrict__ counts,
                                int* __restrict__ offsets, int* __restrict__ cursor,
                                int* __restrict__ tile_e, int* __restrict__ tile_start,
                                int* __restrict__ tile_rows, int* __restrict__ n_mtiles,
                                float* __restrict__ aux_out)
{
  if (threadIdx.x == 0){
    int off = 0, m = 0;
    for (int e = 0; e < 8; e++){
      offsets[e] = off; cursor[e] = off;
      int c = counts[e];
      for (int by = 0; by * 128 < c; by++){
        tile_e[m] = e;
        tile_start[m] = off + by * 128;
        int r = c - by * 128;
        tile_rows[m] = r < 128 ? r : 128;
        m++;
      }
      off += c;
    }
    n_mtiles[0] = m;
    double aux = 0.0;
    for (int e = 0; e < 8; e++){
      double d = prob_sums[e] / 4096.0 - 0.125;
      aux += d * d;
    }
    aux_out[0] = (float)(aux / 8.0);
  }
}

// ---------------- scatter: counting-sort tokens + x -> bf16 grouped ----------------
__global__ __launch_bounds__(256) void scatter_kernel(
    const float* __restrict__ x, const int* __restrict__ expert_id, const float* __restrict__ wtok,
    int* __restrict__ cursor, int* __restrict__ token_of, float* __restrict__ gw,
    unsigned short* __restrict__ Xg)
{
  int t = blockIdx.x;
  __shared__ int spos;
  if (threadIdx.x == 0){
    int e = expert_id[t];
    int p = atomicAdd(&cursor[e], 1);
    spos = p;
    token_of[p] = t; gw[p] = wtok[t];
  }
  __syncthreads();
  int pos = spos;
  float4 v = ((const float4*)(x + (size_t)t * D_DIM))[threadIdx.x];
  ushort4 o; o.x = f2bf(v.x); o.y = f2bf(v.y); o.z = f2bf(v.z); o.w = f2bf(v.w);
  ((ushort4*)(Xg + (size_t)pos * D_DIM))[threadIdx.x] = o;
}

// ---------------- weight transpose+convert: fp32 [E][K][N] -> bf16 [E][N][K] ----------------
__global__ __launch_bounds__(256) void transpose_w(
    const float* __restrict__ W, unsigned short* __restrict__ WT, int K, int N)
{
  int e = blockIdx.z;
  int k0 = blockIdx.x * 64;
  int n0 = blockIdx.y * 64;
  __shared__ float tile[64][65];
  const float* src = W + (size_t)e * K * N;
  int tid = threadIdx.x;
  int r = tid >> 4;              // 0..15
  int c4 = (tid & 15) * 4;       // 0..60
  #pragma unroll
  for (int j = 0; j < 4; j++){
    int k = r + j * 16;
    float4 v = *(const float4*)(src + (size_t)(k0 + k) * N + n0 + c4);
    tile[k][c4] = v.x; tile[k][c4 + 1] = v.y; tile[k][c4 + 2] = v.z; tile[k][c4 + 3] = v.w;
  }
  __syncthreads();
  unsigned short* dst = WT + (size_t)e * N * K;
  int n = tid >> 2;              // 0..63
  #pragma unroll
  for (int h = 0; h < 2; h++){
    int s = (tid & 3) + h * 4;   // 8-element k-segment 0..7
    unsigned short buf[8];
    #pragma unroll
    for (int j = 0; j < 8; j++) buf[j] = f2bf(tile[s * 8 + j][n]);
    *(s16x8*)(dst + (size_t)(n0 + n) * K + k0 + s * 8) = *(s16x8*)buf;
  }
}

// ---------------- grouped GEMM, prefetch-dbuf structure ----------------
// Tile 128 x BN, BK=64, 256 threads (2x2 waves), mfma 16x16x32 bf16.
// K-loop: stage tile kt+1 into buf^1 (global_load_lds w=16), compute tile kt, ONE
// __syncthreads per step (its vmcnt(0)+lgkmcnt(0) drain lands after the MFMA phase,
// hiding HBM latency).  LDS rows are 128 B; fragment reads would be 16-way bank
// conflicts, so the 16B slot index is XOR-swizzled with (row&7) — realized by
// permuting the per-lane GLOBAL source address (linear LDS dest, rule "both sides"),
// and applying the same XOR on the ds_read address.  Tiles come from a device-built
// flat list (no no-op blocks).
template<int K, int N, int BN, int PASS2>
__global__ __launch_bounds__(256, 2) void ffn_gemm(
    const unsigned short* __restrict__ A,
    const unsigned short* __restrict__ BT,
    const float* __restrict__ bias,
    const int* __restrict__ tile_e, const int* __restrict__ tile_start,
    const int* __restrict__ tile_rows, const int* __restrict__ n_mtiles,
    const int* __restrict__ token_of, const float* __restrict__ gw,
    unsigned short* __restrict__ Hout,   // pass1: bf16 gelu output
    float* __restrict__ Fout)            // pass2: fp32 scattered rows, (acc+b2)*w
{
  int mt = blockIdx.y;
  if (mt >= n_mtiles[0]) return;
  int e = tile_e[mt], tstart = tile_start[mt], trows = tile_rows[mt];
  int bx = blockIdx.x;
  int tid = threadIdx.x, lane = tid & 63;
  int wv = __builtin_amdgcn_readfirstlane(tid >> 6);
  int wm = wv & 1, wn = wv >> 1;
  constexpr int NI  = BN / 32;    // accumulator cols per wave /16 (4 or 2)
  constexpr int NBW = BN / 32;    // B chunks staged per wave (4 or 2)
  constexpr int NK  = K / 64;

  __shared__ unsigned short sA[2][128 * 64];   // 2 x 16 KB
  __shared__ unsigned short sB[2][BN * 64];    // 2 x 16/8 KB

  // staging: chunk = 8 rows x 64 k = 1 KB; lane i -> row = c*8 + (i>>3),
  // physical 16B slot p = i&7, must hold logical k-seg s = p ^ (row&7).
  int r8  = lane >> 3;
  int swz = ((lane & 7) ^ r8) * 8;   // element offset of this lane's logical k-seg

  const unsigned short* ap[4]; int al[4];
  #pragma unroll
  for (int j = 0; j < 4; j++){
    int c = wv * 4 + j;                 // A chunk 0..15
    int row = c * 8 + r8;
    int rr = row < trows ? row : 0;     // clamp to a valid grouped row; masked at store
    ap[j] = A + (size_t)(tstart + rr) * K + swz;
    al[j] = c * 512;
  }
  const unsigned short* bp[NBW]; int bl[NBW];
  #pragma unroll
  for (int j = 0; j < NBW; j++){
    int c = wv * NBW + j;               // B chunk 0..BN/8-1
    int n = bx * BN + c * 8 + r8;
    bp[j] = BT + ((size_t)e * N + n) * K + swz;
    bl[j] = c * 512;
  }

  f32x4 accv[4][NI];
  #pragma unroll
  for (int mi = 0; mi < 4; mi++)
    #pragma unroll
    for (int ni = 0; ni < NI; ni++) accv[mi][ni] = (f32x4){0.f, 0.f, 0.f, 0.f};

  // prologue: stage tile 0 into buf 0
  #pragma unroll
  for (int j = 0; j < 4; j++){ gld_lds16(ap[j], &sA[0][al[j]]); ap[j] += 64; }
  #pragma unroll
  for (int j = 0; j < NBW; j++){ gld_lds16(bp[j], &sB[0][bl[j]]); bp[j] += 64; }
  __syncthreads();

  int col = lane & 15, quad = lane >> 4, rx = col & 7;
  for (int kt = 0; kt < NK; ++kt){
    int cur = kt & 1;
    if (kt + 1 < NK){                   // prefetch next tile into the other buffer
      #pragma unroll
      for (int j = 0; j < 4; j++){ gld_lds16(ap[j], &sA[cur ^ 1][al[j]]); ap[j] += 64; }
      #pragma unroll
      for (int j = 0; j < NBW; j++){ gld_lds16(bp[j], &sB[cur ^ 1][bl[j]]); bp[j] += 64; }
    }
    #pragma unroll
    for (int kh = 0; kh < 2; kh++){
      int ps = ((kh * 4 + quad) ^ rx) * 8;   // swizzled 16B slot
      s16x8 af[4], bfr[NI];
      #pragma unroll
      for (int mi = 0; mi < 4; mi++)
        af[mi] = *(const s16x8*)&sA[cur][(wm * 64 + mi * 16 + col) * 64 + ps];
      #pragma unroll
      for (int ni = 0; ni < NI; ni++)
        bfr[ni] = *(const s16x8*)&sB[cur][(wn * (BN / 2) + ni * 16 + col) * 64 + ps];
      #pragma unroll
      for (int mi = 0; mi < 4; mi++)
        #pragma unroll
        for (int ni = 0; ni < NI; ni++)
          accv[mi][ni] = __builtin_amdgcn_mfma_f32_16x16x32_bf16(af[mi], bfr[ni], accv[mi][ni], 0, 0, 0);
    }
    __syncthreads();   // vmcnt(0)+lgkmcnt(0)+barrier: prefetch landed, reads done
  }

  float bv[NI];
  #pragma unroll
  for (int ni = 0; ni < NI; ni++)
    bv[ni] = bias[(size_t)e * N + bx * BN + wn * (BN / 2) + ni * 16 + col];

  if (PASS2 == 0){
    #pragma unroll
    for (int mi = 0; mi < 4; mi++){
      int rbase = wm * 64 + mi * 16 + quad * 4;
      #pragma unroll
      for (int r = 0; r < 4; r++){
        int row = rbase + r;
        if (row < trows){
          size_t orow = (size_t)(tstart + row) * N + bx * BN + wn * (BN / 2) + col;
          #pragma unroll
          for (int ni = 0; ni < NI; ni++){
            float v = accv[mi][ni][r] + bv[ni];
            float g = 0.5f * v * (1.0f + erff(v * 0.70710678118654752f));  // exact gelu
            Hout[orow + ni * 16] = f2bf(g);
          }
        }
      }
    }
  } else {
    #pragma unroll
    for (int mi = 0; mi < 4; mi++){
      int rbase = wm * 64 + mi * 16 + quad * 4;
      #pragma unroll
      for (int r = 0; r < 4; r++){
        int row = rbase + r;
        if (row < trows){
          int pos = tstart + row;
          int tok = token_of[pos];
          float wgt = gw[pos];
          size_t orow = (size_t)tok * N + bx * BN + wn * (BN / 2) + col;
          #pragma unroll
          for (int ni = 0; ni < NI; ni++)
            Fout[orow + ni * 16] = (accv[mi][ni][r] + bv[ni]) * wgt;
        }
      }
    }
  }
}

extern "C" void kernel_launch(void* const* d_in, const int* in_sizes, int n_in,
                              void* d_out, int out_size, void* d_ws, size_t ws_size,
                              hipStream_t stream)
{
  const float* x      = (const float*)d_in[0];
  const float* gumbel = (const float*)d_in[1];
  const float* rw     = (const float*)d_in[2];
  const float* rb     = (const float*)d_in[3];
  const float* w1     = (const float*)d_in[4];
  const float* b1     = (const float*)d_in[5];
  const float* w2     = (const float*)d_in[6];
  const float* b2     = (const float*)d_in[7];
  float* out = (float*)d_out;

  char* ws = (char*)d_ws;
  double* prob_sums = (double*)(ws + 0);        // 64 B
  int* counts     = (int*)(ws + 64);
  int* offsets    = (int*)(ws + 96);
  int* cursor     = (int*)(ws + 128);
  int* n_mtiles   = (int*)(ws + 160);
  int* tile_e     = (int*)(ws + 192);           // 48 ints
  int* tile_start = (int*)(ws + 384);
  int* tile_rows  = (int*)(ws + 576);
  int* expert_id  = (int*)(ws + 1024);                    // 16 KB
  float* wtok     = (float*)(ws + 1024 + 16384);          // 16 KB
  int* token_of   = (int*)(ws + 1024 + 2 * 16384);        // 16 KB
  float* gw       = (float*)(ws + 1024 + 3 * 16384);      // 16 KB -> ends at 66560
  unsigned short* Xg     = (unsigned short*)(ws + 66560);             // 8 MB bf16
  unsigned short* hidden = (unsigned short*)(ws + 66560 + 8388608);   // 32 MB bf16
  unsigned short* wT     = (unsigned short*)(ws + 66560 + 8388608 + 33554432); // 64 MB, shared w1T/w2T

  hipMemsetAsync(ws, 0, 256, stream);   // zero atomic accumulators (capture-safe)

  router_kernel<<<1024, 256, 0, stream>>>(x, gumbel, rw, rb, expert_id, wtok, prob_sums, counts);
  finalize_kernel<<<1, 64, 0, stream>>>(prob_sums, counts, offsets, cursor,
                                        tile_e, tile_start, tile_rows, n_mtiles, out + 4194304);
  scatter_kernel<<<4096, 256, 0, stream>>>(x, expert_id, wtok, cursor, token_of, gw, Xg);

  // w1T = bf16 transpose of w1: [8][1024][4096] -> [8][4096][1024]
  transpose_w<<<dim3(16, 64, 8), 256, 0, stream>>>(w1, wT, 1024, 4096);
  // hidden = gelu(Xg @ w1[e] + b1[e])   (M=cnt_e grouped, N=4096, K=1024)
  ffn_gemm<1024, 4096, 128, 0><<<dim3(32, MAX_TILES), 256, 0, stream>>>(
      Xg, wT, b1, tile_e, tile_start, tile_rows, n_mtiles, nullptr, nullptr, hidden, nullptr);

  // w2T = bf16 transpose of w2: [8][4096][1024] -> [8][1024][4096]  (reuses wT slab)
  transpose_w<<<dim3(64, 16, 8), 256, 0, stream>>>(w2, wT, 4096, 1024);
  // out[tok] = w_t * (hidden @ w2[e] + b2[e])   (M=cnt_e grouped, N=1024, K=4096)
  ffn_gemm<4096, 1024, 64, 1><<<dim3(16, MAX_TILES), 256, 0, stream>>>(
      hidden, wT, b2, tile_e, tile_start, tile_rows, n_mtiles, token_of, gw, nullptr, out);
}

// Round 2
// 544.805 us; speedup vs baseline: 1.0842x; 1.0325x over previous
//
#include <hip/hip_runtime.h>
#include <math.h>

#define D_DIM 1024
#define MAX_TILES 40   // worst-case sum of ceil(cnt_e/128) = 32 + 7 < 40

typedef __attribute__((ext_vector_type(4))) float f32x4;
typedef __attribute__((ext_vector_type(8))) short s16x8;

__device__ __forceinline__ unsigned short f2bf(float f){
  union { float f; unsigned u; } v; v.f = f;
  unsigned r = v.u + 0x7FFFu + ((v.u >> 16) & 1u);   // RNE; inputs finite
  return (unsigned short)(r >> 16);
}

__device__ __forceinline__ void gld_lds16(const unsigned short* g, unsigned short* l){
  __builtin_amdgcn_global_load_lds(
      (const __attribute__((address_space(1))) unsigned int*)g,
      (__attribute__((address_space(3))) unsigned int*)l, 16, 0, 0);
}

template<int N>
__device__ __forceinline__ void wait_vmcnt(){
  if constexpr (N == 8)      asm volatile("s_waitcnt vmcnt(8)" ::: "memory");
  else if constexpr (N == 6) asm volatile("s_waitcnt vmcnt(6)" ::: "memory");
  else                       asm volatile("s_waitcnt vmcnt(0)" ::: "memory");
  __builtin_amdgcn_sched_barrier(0);
}

// ---------------- router: fp64 logits, argmax, w_t, aux-loss sums ----------------
__global__ __launch_bounds__(256) void router_kernel(
    const float* __restrict__ x, const float* __restrict__ gumbel,
    const float* __restrict__ rw, const float* __restrict__ rb,
    int* __restrict__ expert_id, float* __restrict__ wtok,
    double* __restrict__ prob_sums, int* __restrict__ counts)
{
  int wave = threadIdx.x >> 6, lane = threadIdx.x & 63;
  int t = blockIdx.x * 4 + wave;
  const float* xr = x + (size_t)t * D_DIM;
  double acc[8];
  #pragma unroll
  for (int e = 0; e < 8; e++) acc[e] = 0.0;
  #pragma unroll
  for (int i = 0; i < 16; i++){
    int d = i * 64 + lane;
    double xv = (double)xr[d];
    const float4* rwp = (const float4*)(rw + (size_t)d * 8);
    float4 r0 = rwp[0], r1 = rwp[1];
    acc[0] += xv * (double)r0.x; acc[1] += xv * (double)r0.y;
    acc[2] += xv * (double)r0.z; acc[3] += xv * (double)r0.w;
    acc[4] += xv * (double)r1.x; acc[5] += xv * (double)r1.y;
    acc[6] += xv * (double)r1.z; acc[7] += xv * (double)r1.w;
  }
  #pragma unroll
  for (int e = 0; e < 8; e++){
    #pragma unroll
    for (int off = 32; off; off >>= 1) acc[e] += __shfl_xor(acc[e], off);
  }
  double logit[8], z[8];
  #pragma unroll
  for (int e = 0; e < 8; e++){
    logit[e] = acc[e] + (double)rb[e];
    z[e] = logit[e] + (double)gumbel[(size_t)t * 8 + e];
  }
  int amax = 0;
  #pragma unroll
  for (int e = 1; e < 8; e++) if (z[e] > z[amax]) amax = e;   // first-max like jnp.argmax
  float zm = (float)z[amax];
  float se = 0.f;
  #pragma unroll
  for (int e = 0; e < 8; e++) se += expf((float)z[e] - zm);
  float y = 1.f / se;                 // y_soft at argmax
  float w = (1.0f - y) + y;           // replicate ref fp32 arithmetic
  double lm = logit[0];
  #pragma unroll
  for (int e = 1; e < 8; e++) lm = fmax(lm, logit[e]);
  float p[8]; float ps = 0.f;
  #pragma unroll
  for (int e = 0; e < 8; e++){ p[e] = expf((float)(logit[e] - lm)); ps += p[e]; }
  float inv = 1.f / ps;

  __shared__ float sprob[4][8];
  if (lane == 0){
    expert_id[t] = amax; wtok[t] = w;
    atomicAdd(&counts[amax], 1);
    #pragma unroll
    for (int e = 0; e < 8; e++) sprob[wave][e] = p[e] * inv;
  }
  __syncthreads();
  if (threadIdx.x < 8){
    double s = (double)sprob[0][threadIdx.x] + (double)sprob[1][threadIdx.x]
             + (double)sprob[2][threadIdx.x] + (double)sprob[3][threadIdx.x];
    atomicAdd(&prob_sums[threadIdx.x], s);
  }
}

// ---------------- finalize: offsets/cursors + flattened 128-row tile list + aux loss ----------------
__global__ void finalize_kernel(const double* __restrict__ prob_sums, const int* __restrict__ counts,
                                int* __restrict__ offsets, int* __restrict__ cursor,
                                int* __restrict__ tile_e, int* __restrict__ tile_start,
                                int* __restrict__ tile_rows, int* __restrict__ n_mtiles,
                                float* __restrict__ aux_out)
{
  if (threadIdx.x == 0){
    int off = 0, m = 0;
    for (int e = 0; e < 8; e++){
      offsets[e] = off; cursor[e] = off;
      int c = counts[e];
      for (int by = 0; by * 128 < c; by++){
        tile_e[m] = e;
        tile_start[m] = off + by * 128;
        int r = c - by * 128;
        tile_rows[m] = r < 128 ? r : 128;
        m++;
      }
      off += c;
    }
    n_mtiles[0] = m;
    double aux = 0.0;
    for (int e = 0; e < 8; e++){
      double d = prob_sums[e] / 4096.0 - 0.125;
      aux += d * d;
    }
    aux_out[0] = (float)(aux / 8.0);
  }
}

// ---------------- scatter: counting-sort tokens + x -> bf16 grouped ----------------
__global__ __launch_bounds__(256) void scatter_kernel(
    const float* __restrict__ x, const int* __restrict__ expert_id, const float* __restrict__ wtok,
    int* __restrict__ cursor, int* __restrict__ token_of, float* __restrict__ gw,
    unsigned short* __restrict__ Xg)
{
  int t = blockIdx.x;
  __shared__ int spos;
  if (threadIdx.x == 0){
    int e = expert_id[t];
    int p = atomicAdd(&cursor[e], 1);
    spos = p;
    token_of[p] = t; gw[p] = wtok[t];
  }
  __syncthreads();
  int pos = spos;
  float4 v = ((const float4*)(x + (size_t)t * D_DIM))[threadIdx.x];
  ushort4 o; o.x = f2bf(v.x); o.y = f2bf(v.y); o.z = f2bf(v.z); o.w = f2bf(v.w);
  ((ushort4*)(Xg + (size_t)pos * D_DIM))[threadIdx.x] = o;
}

// ---------------- weight transpose+convert: fp32 [E][K][N] -> bf16 [E][N][K] ----------------
__global__ __launch_bounds__(256) void transpose_w(
    const float* __restrict__ W, unsigned short* __restrict__ WT, int K, int N)
{
  int e = blockIdx.z;
  int k0 = blockIdx.x * 64;
  int n0 = blockIdx.y * 64;
  __shared__ float tile[64][65];
  const float* src = W + (size_t)e * K * N;
  int tid = threadIdx.x;
  int r = tid >> 4;              // 0..15
  int c4 = (tid & 15) * 4;       // 0..60
  #pragma unroll
  for (int j = 0; j < 4; j++){
    int k = r + j * 16;
    float4 v = *(const float4*)(src + (size_t)(k0 + k) * N + n0 + c4);
    tile[k][c4] = v.x; tile[k][c4 + 1] = v.y; tile[k][c4 + 2] = v.z; tile[k][c4 + 3] = v.w;
  }
  __syncthreads();
  // write phase: idx = it*256+tid; n = idx>>3, s = idx&7  ->  8 lanes cover one n-row
  // with 8 x 16B = 128B contiguous along K (better DRAM sectors than 64B chunks).
  unsigned short* dst = WT + (size_t)e * N * K;
  #pragma unroll
  for (int it = 0; it < 2; it++){
    int idx = it * 256 + tid;
    int n = idx >> 3;            // 0..63
    int s = idx & 7;             // 16B k-segment
    unsigned short buf[8];
    #pragma unroll
    for (int j = 0; j < 8; j++) buf[j] = f2bf(tile[s * 8 + j][n]);
    *(s16x8*)(dst + (size_t)(n0 + n) * K + k0 + s * 8) = *(s16x8*)buf;
  }
}

// ---------------- grouped GEMM, counted-vmcnt double-buffer pipeline ----------------
// Tile 128 x BN, BK=64, 256 threads (2x2 waves), mfma 16x16x32 bf16.
// K-loop per step kt (T3+T4 structure; raw barriers, loads in flight ACROSS barriers):
//   wait_vmcnt(LOADS) ; barrier        -> tile kt landed, tile kt+1 still in flight
//   ds_read ALL fragments of buf[cur] ; lgkmcnt(0) ; sched_barrier ; barrier
//   issue stage(tile kt+2 -> buf[cur])  (never waited this iteration)
//   setprio(1) ; 2x(16|8) MFMA ; setprio(0)
// Each tile's loads get a full iteration of compute to land -> L2 latency hidden.
// LDS XOR-swizzle (slot ^= row&7) via pre-swizzled global source, same XOR on reads.
template<int K, int N, int BN, int PASS2>
__global__ __launch_bounds__(256, 2) void ffn_gemm(
    const unsigned short* __restrict__ A,
    const unsigned short* __restrict__ BT,
    const float* __restrict__ bias,
    const int* __restrict__ tile_e, const int* __restrict__ tile_start,
    const int* __restrict__ tile_rows, const int* __restrict__ n_mtiles,
    const int* __restrict__ token_of, const float* __restrict__ gw,
    unsigned short* __restrict__ Hout,   // pass1: bf16 gelu output
    float* __restrict__ Fout)            // pass2: fp32 scattered rows, (acc+b2)*w
{
  int mt = blockIdx.y;
  if (mt >= n_mtiles[0]) return;
  int e = tile_e[mt], tstart = tile_start[mt], trows = tile_rows[mt];
  int bx = blockIdx.x;
  int tid = threadIdx.x, lane = tid & 63;
  int wv = __builtin_amdgcn_readfirstlane(tid >> 6);
  int wm = wv & 1, wn = wv >> 1;
  constexpr int NI    = BN / 32;    // accumulator cols per wave /16 (4 or 2)
  constexpr int NBW   = BN / 32;    // B chunks staged per wave (4 or 2)
  constexpr int NK    = K / 64;
  constexpr int LOADS = 4 + NBW;    // global_load_lds per wave per tile (8 or 6)

  __shared__ unsigned short sA[2][128 * 64];   // 2 x 16 KB
  __shared__ unsigned short sB[2][BN * 64];    // 2 x 16/8 KB

  // staging: chunk = 8 rows x 64 k = 1 KB; lane i -> row = c*8 + (i>>3),
  // physical 16B slot p = i&7 must hold logical k-seg s = p ^ (row&7).
  int r8  = lane >> 3;
  int swz = ((lane & 7) ^ r8) * 8;   // element offset of this lane's logical k-seg

  const unsigned short* ap[4]; int al[4];
  #pragma unroll
  for (int j = 0; j < 4; j++){
    int c = wv * 4 + j;                 // A chunk 0..15
    int row = c * 8 + r8;
    int rr = row < trows ? row : 0;     // clamp to a valid grouped row; masked at store
    ap[j] = A + (size_t)(tstart + rr) * K + swz;
    al[j] = c * 512;
  }
  const unsigned short* bp[NBW]; int bl[NBW];
  #pragma unroll
  for (int j = 0; j < NBW; j++){
    int c = wv * NBW + j;               // B chunk 0..BN/8-1
    int n = bx * BN + c * 8 + r8;
    bp[j] = BT + ((size_t)e * N + n) * K + swz;
    bl[j] = c * 512;
  }

  f32x4 accv[4][NI];
  #pragma unroll
  for (int mi = 0; mi < 4; mi++)
    #pragma unroll
    for (int ni = 0; ni < NI; ni++) accv[mi][ni] = (f32x4){0.f, 0.f, 0.f, 0.f};

  // prologue: stage tiles 0 and 1 (2*LOADS outstanding per wave)
  #pragma unroll
  for (int b = 0; b < 2; b++){
    #pragma unroll
    for (int j = 0; j < 4; j++){ gld_lds16(ap[j], &sA[b][al[j]]); ap[j] += 64; }
    #pragma unroll
    for (int j = 0; j < NBW; j++){ gld_lds16(bp[j], &sB[b][bl[j]]); bp[j] += 64; }
  }

  int col = lane & 15, quad = lane >> 4, rx = col & 7;
  for (int kt = 0; kt < NK; ++kt){
    int cur = kt & 1;
    // (1) tile kt landed; tile kt+1's LOADS stay in flight
    if (kt + 1 < NK) wait_vmcnt<LOADS>(); else wait_vmcnt<0>();
    __builtin_amdgcn_s_barrier();
    // (2) read ALL fragments of this K-step into registers
    s16x8 af[2][4], bfr[2][NI];
    #pragma unroll
    for (int kh = 0; kh < 2; kh++){
      int ps = ((kh * 4 + quad) ^ rx) * 8;   // swizzled 16B slot
      #pragma unroll
      for (int mi = 0; mi < 4; mi++)
        af[kh][mi] = *(const s16x8*)&sA[cur][(wm * 64 + mi * 16 + col) * 64 + ps];
      #pragma unroll
      for (int ni = 0; ni < NI; ni++)
        bfr[kh][ni] = *(const s16x8*)&sB[cur][(wn * (BN / 2) + ni * 16 + col) * 64 + ps];
    }
    asm volatile("s_waitcnt lgkmcnt(0)" ::: "memory");
    __builtin_amdgcn_sched_barrier(0);
    __builtin_amdgcn_s_barrier();          // all waves done reading buf[cur]
    // (3) overwrite buf[cur] with tile kt+2 (issue only, no wait)
    if (kt + 2 < NK){
      #pragma unroll
      for (int j = 0; j < 4; j++){ gld_lds16(ap[j], &sA[cur][al[j]]); ap[j] += 64; }
      #pragma unroll
      for (int j = 0; j < NBW; j++){ gld_lds16(bp[j], &sB[cur][bl[j]]); bp[j] += 64; }
    }
    // (4) MFMA on registers, overlapping the in-flight loads
    __builtin_amdgcn_s_setprio(1);
    #pragma unroll
    for (int kh = 0; kh < 2; kh++)
      #pragma unroll
      for (int mi = 0; mi < 4; mi++)
        #pragma unroll
        for (int ni = 0; ni < NI; ni++)
          accv[mi][ni] = __builtin_amdgcn_mfma_f32_16x16x32_bf16(af[kh][mi], bfr[kh][ni], accv[mi][ni], 0, 0, 0);
    __builtin_amdgcn_s_setprio(0);
  }

  float bv[NI];
  #pragma unroll
  for (int ni = 0; ni < NI; ni++)
    bv[ni] = bias[(size_t)e * N + bx * BN + wn * (BN / 2) + ni * 16 + col];

  if (PASS2 == 0){
    #pragma unroll
    for (int mi = 0; mi < 4; mi++){
      int rbase = wm * 64 + mi * 16 + quad * 4;
      #pragma unroll
      for (int r = 0; r < 4; r++){
        int row = rbase + r;
        if (row < trows){
          size_t orow = (size_t)(tstart + row) * N + bx * BN + wn * (BN / 2) + col;
          #pragma unroll
          for (int ni = 0; ni < NI; ni++){
            float v = accv[mi][ni][r] + bv[ni];
            float g = 0.5f * v * (1.0f + erff(v * 0.70710678118654752f));  // exact gelu
            Hout[orow + ni * 16] = f2bf(g);
          }
        }
      }
    }
  } else {
    #pragma unroll
    for (int mi = 0; mi < 4; mi++){
      int rbase = wm * 64 + mi * 16 + quad * 4;
      #pragma unroll
      for (int r = 0; r < 4; r++){
        int row = rbase + r;
        if (row < trows){
          int pos = tstart + row;
          int tok = token_of[pos];
          float wgt = gw[pos];
          size_t orow = (size_t)tok * N + bx * BN + wn * (BN / 2) + col;
          #pragma unroll
          for (int ni = 0; ni < NI; ni++)
            Fout[orow + ni * 16] = (accv[mi][ni][r] + bv[ni]) * wgt;
        }
      }
    }
  }
}

extern "C" void kernel_launch(void* const* d_in, const int* in_sizes, int n_in,
                              void* d_out, int out_size, void* d_ws, size_t ws_size,
                              hipStream_t stream)
{
  const float* x      = (const float*)d_in[0];
  const float* gumbel = (const float*)d_in[1];
  const float* rw     = (const float*)d_in[2];
  const float* rb     = (const float*)d_in[3];
  const float* w1     = (const float*)d_in[4];
  const float* b1     = (const float*)d_in[5];
  const float* w2     = (const float*)d_in[6];
  const float* b2     = (const float*)d_in[7];
  float* out = (float*)d_out;

  char* ws = (char*)d_ws;
  double* prob_sums = (double*)(ws + 0);        // 64 B
  int* counts     = (int*)(ws + 64);
  int* offsets    = (int*)(ws + 96);
  int* cursor     = (int*)(ws + 128);
  int* n_mtiles   = (int*)(ws + 160);
  int* tile_e     = (int*)(ws + 192);           // 48 ints
  int* tile_start = (int*)(ws + 384);
  int* tile_rows  = (int*)(ws + 576);
  int* expert_id  = (int*)(ws + 1024);                    // 16 KB
  float* wtok     = (float*)(ws + 1024 + 16384);          // 16 KB
  int* token_of   = (int*)(ws + 1024 + 2 * 16384);        // 16 KB
  float* gw       = (float*)(ws + 1024 + 3 * 16384);      // 16 KB -> ends at 66560
  unsigned short* Xg     = (unsigned short*)(ws + 66560);             // 8 MB bf16
  unsigned short* hidden = (unsigned short*)(ws + 66560 + 8388608);   // 32 MB bf16
  unsigned short* wT     = (unsigned short*)(ws + 66560 + 8388608 + 33554432); // 64 MB, shared w1T/w2T

  hipMemsetAsync(ws, 0, 256, stream);   // zero atomic accumulators (capture-safe)

  router_kernel<<<1024, 256, 0, stream>>>(x, gumbel, rw, rb, expert_id, wtok, prob_sums, counts);
  finalize_kernel<<<1, 64, 0, stream>>>(prob_sums, counts, offsets, cursor,
                                        tile_e, tile_start, tile_rows, n_mtiles, out + 4194304);
  scatter_kernel<<<4096, 256, 0, stream>>>(x, expert_id, wtok, cursor, token_of, gw, Xg);

  // w1T = bf16 transpose of w1: [8][1024][4096] -> [8][4096][1024]
  transpose_w<<<dim3(16, 64, 8), 256, 0, stream>>>(w1, wT, 1024, 4096);
  // hidden = gelu(Xg @ w1[e] + b1[e])   (M=cnt_e grouped, N=4096, K=1024)
  ffn_gemm<1024, 4096, 128, 0><<<dim3(32, MAX_TILES), 256, 0, stream>>>(
      Xg, wT, b1, tile_e, tile_start, tile_rows, n_mtiles, nullptr, nullptr, hidden, nullptr);

  // w2T = bf16 transpose of w2: [8][4096][1024] -> [8][1024][4096]  (reuses wT slab)
  transpose_w<<<dim3(64, 16, 8), 256, 0, stream>>>(w2, wT, 4096, 1024);
  // out[tok] = w_t * (hidden @ w2[e] + b2[e])   (M=cnt_e grouped, N=1024, K=4096)
  ffn_gemm<4096, 1024, 64, 1><<<dim3(16, MAX_TILES), 256, 0, stream>>>(
      hidden, wT, b2, tile_e, tile_start, tile_rows, n_mtiles, token_of, gw, nullptr, out);
}